// Round 3
// baseline (132.459 us; speedup 1.0000x reference)
//
#include <hip/hip_runtime.h>
#include <math.h>

// SpatialEncodeAgent: segment_max of agent_encodings (N,64) into a B*100*100
// grid, output [B, C, S, S] f32, 0 for empty cells.
//
// Round-3: linked-list gather (round 2, 131 us) with three fixes:
//  - custom init_head kernel (replaces rocclr fillBuffer in the graph)
//  - gather blocks = 32 cells on a 2D (x=chunk, y=batch) grid so output
//    writes are 128B-aligned full-line segments per channel (round-2's
//    16-cell blocks wrote 64B half-lines shared across blocks/XCDs ->
//    read-for-ownership + write amplification)
//  - next-pointer prefetch before the enc row read in the chain walk
// fmax is exactly commutative -> chain-order nondeterminism is bitwise-safe.

#define S_DIM 100
#define CELLS_PER_B (S_DIM * S_DIM)  // 10000
#define C_DIM 64
#define CPB 32  // cells per gather block

__global__ void init_head(int* __restrict__ head, int n) {
    const int stride = gridDim.x * blockDim.x;
    for (int i = blockIdx.x * blockDim.x + threadIdx.x; i < n; i += stride)
        head[i] = -1;
}

__global__ void build_lists(const int* __restrict__ coords,
                            int* __restrict__ head, int* __restrict__ next,
                            int n) {
    const int stride = gridDim.x * blockDim.x;
    for (int i = blockIdx.x * blockDim.x + threadIdx.x; i < n; i += stride) {
        const int c = coords[i];
        next[i] = atomicExch(&head[c], i);
    }
}

// Block = 512 threads = 32 cells x 16 lanes; each lane owns 4 channels.
// Grid: x = ceil(10000/32) = 313 chunks within a batch, y = batch.
__global__ __launch_bounds__(512) void gather_max(
    const float* __restrict__ enc, const int* __restrict__ head,
    const int* __restrict__ next, float* __restrict__ out) {
    __shared__ float tile[CPB][C_DIM + 1];  // +1: conflict-free column reads
    const int tid = threadIdx.x;
    const int cl = tid >> 4;         // local cell 0..31
    const int c4 = (tid & 15) << 2;  // channel base 0,4,...,60
    const int b = blockIdx.y;
    const int rem0 = blockIdx.x * CPB;      // 128B-aligned within batch plane
    const int rem = rem0 + cl;

    float4 m = make_float4(-INFINITY, -INFINITY, -INFINITY, -INFINITY);
    int agent = (rem < CELLS_PER_B) ? head[b * CELLS_PER_B + rem] : -1;
    const bool occupied = (agent >= 0);
    while (agent >= 0) {
        const int nxt = next[agent];  // prefetch: independent of enc read
        const float4 v =
            *reinterpret_cast<const float4*>(enc + (size_t)agent * C_DIM + c4);
        m.x = fmaxf(m.x, v.x);
        m.y = fmaxf(m.y, v.y);
        m.z = fmaxf(m.z, v.z);
        m.w = fmaxf(m.w, v.w);
        agent = nxt;
    }
    if (!occupied) m = make_float4(0.f, 0.f, 0.f, 0.f);
    tile[cl][c4 + 0] = m.x;
    tile[cl][c4 + 1] = m.y;
    tile[cl][c4 + 2] = m.z;
    tile[cl][c4 + 3] = m.w;
    __syncthreads();

    // Write: per channel c, 32 consecutive lanes store 32 consecutive cells
    // = one full 128B line (rem0 is 32-float aligned).
    float* base = out + ((size_t)b * C_DIM) * CELLS_PER_B + rem0;
    const int limit = min(CPB, CELLS_PER_B - rem0);  // 16 on the last chunk
    for (int i = tid; i < CPB * C_DIM; i += 512) {
        const int c = i >> 5;
        const int j = i & 31;
        if (j < limit) base[(size_t)c * CELLS_PER_B + j] = tile[j][c];
    }
}

extern "C" void kernel_launch(void* const* d_in, const int* in_sizes, int n_in,
                              void* d_out, int out_size, void* d_ws, size_t ws_size,
                              hipStream_t stream) {
    const float* enc = (const float*)d_in[1];
    const int* coords = (const int*)d_in[2];
    const int n = in_sizes[2];
    const int ncells = out_size / C_DIM;       // B * 10000
    const int B = ncells / CELLS_PER_B;

    int* head = (int*)d_ws;
    int* next = head + ncells;

    init_head<<<1024, 256, 0, stream>>>(head, ncells);
    build_lists<<<2048, 256, 0, stream>>>(coords, head, next, n);
    dim3 grid((CELLS_PER_B + CPB - 1) / CPB, B);  // (313, B)
    gather_max<<<grid, 512, 0, stream>>>(enc, head, next, (float*)d_out);
}